// Round 5
// baseline (1758.047 us; speedup 1.0000x reference)
//
#include <hip/hip_runtime.h>
#include <math.h>

typedef unsigned short ushort;
typedef unsigned int uint;
typedef __bf16 bf16x8 __attribute__((ext_vector_type(8)));
typedef float f32x4 __attribute__((ext_vector_type(4)));

// Problem constants
#define ZS    128
#define KS    256
#define HS    512
#define BATCH 512
#define TT    32
#define MM    33
#define NB    2304      // 2048 gate cols (n = j*4+gate) + 256 key cols
#define KPAD  800       // 0..256 key_r, 257..271 zero pad, 272..783 h, 784..799 pad
#define HOFF  272
#define LDA   800
#define GTILES 18       // gates n-tiles of 128
#define GSLICE 25       // gates k-slices of 32
#define ESLICE 32       // encoder k-slices of 32
#define GP (GTILES*GSLICE*8192)   // packed gates weights (hi|lo per slice)
#define EP (ESLICE*8192)          // packed encoder weights

static __device__ __forceinline__ float sigf(float x) { return 1.f / (1.f + expf(-x)); }
static __device__ __forceinline__ float bf2f(ushort u) { return __uint_as_float((uint)u << 16); }

// ---------------------------------------------------------------------------
// Weight prep into PACKED per-(tile,slice) streams matching LDS staging order:
// element e of a 4096-el half: n_local = e>>5, k_local = ((e>>3)&3)*8 + (e&7).
// Gates: [tile(18)][slice(25)][hi 4096 | lo 4096]; Encoder likewise (1 tile).
// ---------------------------------------------------------------------------
__global__ void prep_w(const float* __restrict__ W_ih, const float* __restrict__ W_hh,
                       const float* __restrict__ W_key, const float* __restrict__ b_ih,
                       const float* __restrict__ b_hh, const float* __restrict__ b_key,
                       const float* __restrict__ W_enc,
                       ushort* __restrict__ Wpk, ushort* __restrict__ Epk,
                       float* __restrict__ biasN)
{
    int idx = blockIdx.x * 256 + threadIdx.x;
    if (idx < NB) {
        float bv;
        if (idx < 2048) { int j = idx >> 2, gi = idx & 3, r = gi * 512 + j; bv = b_ih[r] + b_hh[r]; }
        else bv = b_key[idx - 2048];
        biasN[idx] = bv;
    }
    if (idx < GP) {
        int tile = idx / (GSLICE * 8192);
        int rem  = idx - tile * (GSLICE * 8192);
        int s    = rem >> 13;
        int e2   = rem & 8191;
        int hi_f = (e2 < 4096);
        int e    = e2 & 4095;
        int n = tile * 128 + (e >> 5);
        int k = s * 32 + ((e >> 3) & 3) * 8 + (e & 7);
        float v = 0.f;
        if (n < 2048) {
            int j = n >> 2, gi = n & 3, r = gi * 512 + j;
            if (k < 257) v = W_ih[r * 257 + k];
            else if (k >= HOFF && k < HOFF + 512) v = W_hh[r * 512 + (k - HOFF)];
        } else {
            if (k >= HOFF && k < HOFF + 512) v = W_key[(n - 2048) * 512 + (k - HOFF)];
        }
        uint u = __float_as_uint(v);
        if (hi_f) Wpk[idx] = (ushort)(u >> 16);
        else {
            float lo = v - __uint_as_float(u & 0xFFFF0000u);
            Wpk[idx] = (ushort)(__float_as_uint(lo) >> 16);
        }
    } else if (idx < GP + EP) {
        int q = idx - GP;
        int s = q >> 13;
        int e2 = q & 8191;
        int hi_f = (e2 < 4096);
        int e = e2 & 4095;
        int n = e >> 5;
        int k = s * 32 + ((e >> 3) & 3) * 8 + (e & 7);
        float v = W_enc[k * 128 + n];
        uint u = __float_as_uint(v);
        if (hi_f) Epk[idx - GP] = (ushort)(u >> 16);
        else {
            float lo = v - __uint_as_float(u & 0xFFFF0000u);
            Epk[idx - GP] = (ushort)(__float_as_uint(lo) >> 16);
        }
    }
}

// ---------------------------------------------------------------------------
// bf16x3 MFMA GEMM, 64(M) x 128(N) tile, 256 thr (4 waves 2x2, wave 32x64).
// Pipeline per slice: barrier -> issue global loads s+1 -> ds_read+MFMA s
// -> ds_write s+1 (vmcnt waits post-MFMA). B pre-packed per slice.
// MODE 0: encoder -> z_pad.  MODE 1: gates (XCD-swizzled grid): cols<2048
// fused LSTM cell; cols>=2048 relu -> Mk[step-1].
// ---------------------------------------------------------------------------
template<int MODE, bool PRESPLIT>
__global__ __launch_bounds__(256)
void gemm_mfma(const float* __restrict__ Af,
               const ushort* __restrict__ Ahi, const ushort* __restrict__ Alo, int lda,
               const ushort* __restrict__ Bpk, int nslice,
               float* __restrict__ out,
               ushort* __restrict__ outHi, ushort* __restrict__ outLo,
               const float* __restrict__ biasN,
               float* __restrict__ cst, float* __restrict__ Mk, int step)
{
    constexpr int AHI = 0, ALO = 2560, BHI = 5120, BLO = 10240;
    constexpr int BUF = 15360;             // ushorts per stage buffer
    __shared__ ushort lds[2 * BUF];        // 61,440 B -> 2 blocks/CU

    const int tid = threadIdx.x;
    int bx, by;
    if (MODE == 0) { bx = 0; by = blockIdx.x; }
    else {           // XCD swizzle: each XCD hosts ~2-3 of 18 weight n-tiles
        int f = blockIdx.x, xc = f & 7, ii = f >> 3;
        int g = xc * GTILES + ii;
        bx = g >> 3; by = g & 7;
    }
    const int row0 = by * 64, n0 = bx * 128;
    const int l = tid & 63, w = tid >> 6, wm = w >> 1, wn = w & 1;
    const int lm = l & 15, kg = (l >> 4) << 3;

    f32x4 acc[2][4];
    const f32x4 zero4 = {0.f, 0.f, 0.f, 0.f};
#pragma unroll
    for (int mi = 0; mi < 2; mi++)
#pragma unroll
        for (int ni = 0; ni < 4; ni++) acc[mi][ni] = zero4;

    // prefetch registers
    float4 avf[2];
    uint4 aHu, aLu;
    uint4 bv[4];

    auto LOADG = [&](int s) {
        const int k0 = s * 32;
        if (PRESPLIT) {
            int r = tid >> 2, c = (tid & 3) << 3;
            aHu = *(const uint4*)(Ahi + (size_t)(row0 + r) * lda + k0 + c);
            aLu = *(const uint4*)(Alo + (size_t)(row0 + r) * lda + k0 + c);
        } else {
#pragma unroll
            for (int i = 0; i < 2; i++) {
                int idx = tid + 256 * i, r = idx >> 3, c = (idx & 7) << 2;
                avf[i] = *(const float4*)(Af + (size_t)(row0 + r) * lda + k0 + c);
            }
        }
        const ushort* bp = Bpk + ((size_t)bx * nslice + s) * 8192;
#pragma unroll
        for (int q = 0; q < 4; q++)
            bv[q] = *(const uint4*)(bp + q * 2048 + tid * 8);
    };
    auto STORE = [&](int buf) {
        ushort* L = lds + buf * BUF;
        if (PRESPLIT) {
            int r = tid >> 2, c = (tid & 3) << 3;
            *(uint4*)&L[AHI + r * 40 + c] = aHu;
            *(uint4*)&L[ALO + r * 40 + c] = aLu;
        } else {
#pragma unroll
            for (int i = 0; i < 2; i++) {
                int idx = tid + 256 * i, r = idx >> 3, c = (idx & 7) << 2;
                uint u0 = __float_as_uint(avf[i].x), u1 = __float_as_uint(avf[i].y);
                uint u2 = __float_as_uint(avf[i].z), u3 = __float_as_uint(avf[i].w);
                uint hp0 = (u1 & 0xFFFF0000u) | (u0 >> 16);
                uint hp1 = (u3 & 0xFFFF0000u) | (u2 >> 16);
                float l0 = avf[i].x - __uint_as_float(u0 & 0xFFFF0000u);
                float l1 = avf[i].y - __uint_as_float(u1 & 0xFFFF0000u);
                float l2 = avf[i].z - __uint_as_float(u2 & 0xFFFF0000u);
                float l3 = avf[i].w - __uint_as_float(u3 & 0xFFFF0000u);
                uint lp0 = (__float_as_uint(l1) & 0xFFFF0000u) | (__float_as_uint(l0) >> 16);
                uint lp1 = (__float_as_uint(l3) & 0xFFFF0000u) | (__float_as_uint(l2) >> 16);
                *(uint2*)&L[AHI + r * 40 + c] = make_uint2(hp0, hp1);
                *(uint2*)&L[ALO + r * 40 + c] = make_uint2(lp0, lp1);
            }
        }
#pragma unroll
        for (int q = 0; q < 2; q++) {
            int idx = tid + 256 * q, r = idx >> 2, c = (idx & 3) << 3;
            *(uint4*)&L[BHI + r * 40 + c] = bv[q];
            *(uint4*)&L[BLO + r * 40 + c] = bv[2 + q];
        }
    };

    LOADG(0);
    STORE(0);
    for (int s = 0; s < nslice; s++) {
        __syncthreads();                    // buf[s&1] visible to all waves
        if (s + 1 < nslice) LOADG(s + 1);   // issued AFTER barrier: overlaps MFMA
        const ushort* L = lds + (s & 1) * BUF;
        bf16x8 ah[2], al2[2], bh[4], bl2[4];
#pragma unroll
        for (int mi = 0; mi < 2; mi++) {
            int r = wm * 32 + mi * 16 + lm;
            ah[mi]  = *(const bf16x8*)&L[AHI + r * 40 + kg];
            al2[mi] = *(const bf16x8*)&L[ALO + r * 40 + kg];
        }
#pragma unroll
        for (int ni = 0; ni < 4; ni++) {
            int r = wn * 64 + ni * 16 + lm;
            bh[ni]  = *(const bf16x8*)&L[BHI + r * 40 + kg];
            bl2[ni] = *(const bf16x8*)&L[BLO + r * 40 + kg];
        }
#pragma unroll
        for (int mi = 0; mi < 2; mi++)
#pragma unroll
            for (int ni = 0; ni < 4; ni++) {
                acc[mi][ni] = __builtin_amdgcn_mfma_f32_16x16x32_bf16(ah[mi],  bh[ni],  acc[mi][ni], 0, 0, 0);
                acc[mi][ni] = __builtin_amdgcn_mfma_f32_16x16x32_bf16(ah[mi],  bl2[ni], acc[mi][ni], 0, 0, 0);
                acc[mi][ni] = __builtin_amdgcn_mfma_f32_16x16x32_bf16(al2[mi], bh[ni],  acc[mi][ni], 0, 0, 0);
            }
        if (s + 1 < nslice) STORE((s + 1) & 1);  // vmcnt waits land here
    }

    const int crow = (l >> 4) << 2;   // C/D: row = (lane>>4)*4 + reg, col = lane&15
    if (MODE == 0) {
#pragma unroll
        for (int mi = 0; mi < 2; mi++)
#pragma unroll
            for (int ni = 0; ni < 4; ni++)
#pragma unroll
                for (int r_ = 0; r_ < 4; r_++) {
                    int m = row0 + wm * 32 + mi * 16 + crow + r_;
                    int z = wn * 64 + ni * 16 + lm;
                    out[(size_t)(m >> 5) * (MM * ZS) + (m & 31) * ZS + z] = acc[mi][ni][r_];
                }
    } else if (bx < 16) {
        // gate cols: exchange via LDS so one thread owns i,f,g,o of 8 units
        __syncthreads();
        float* epi = (float*)lds;            // 64 x 132
#pragma unroll
        for (int mi = 0; mi < 2; mi++)
#pragma unroll
            for (int ni = 0; ni < 4; ni++)
#pragma unroll
                for (int r_ = 0; r_ < 4; r_++) {
                    int ml = wm * 32 + mi * 16 + crow + r_;
                    int nl = wn * 64 + ni * 16 + lm;
                    epi[ml * 132 + nl] = acc[mi][ni][r_] + biasN[n0 + nl];
                }
        __syncthreads();
        int bl_ = tid & 63, jj4 = tid >> 6;
        int b = row0 + bl_;
        int j0 = bx * 32 + jj4 * 8;
        float4 c0 = *(float4*)&cst[(size_t)b * HS + j0];
        float4 c1 = *(float4*)&cst[(size_t)b * HS + j0 + 4];
        float cc[8] = {c0.x, c0.y, c0.z, c0.w, c1.x, c1.y, c1.z, c1.w};
        ushort h_hi[8] __attribute__((aligned(16)));
        ushort h_lo[8] __attribute__((aligned(16)));
#pragma unroll
        for (int u = 0; u < 8; u++) {
            const float* pr = &epi[bl_ * 132 + jj4 * 32 + u * 4];
            float ig = sigf(pr[0]), fg = sigf(pr[1]), gg = tanhf(pr[2]), og = sigf(pr[3]);
            float cn = fg * cc[u] + ig * gg;
            float hv = og * tanhf(cn);
            cc[u] = cn;
            uint uu = __float_as_uint(hv);
            h_hi[u] = (ushort)(uu >> 16);
            float lo = hv - __uint_as_float(uu & 0xFFFF0000u);
            h_lo[u] = (ushort)(__float_as_uint(lo) >> 16);
        }
        *(float4*)&cst[(size_t)b * HS + j0]     = make_float4(cc[0], cc[1], cc[2], cc[3]);
        *(float4*)&cst[(size_t)b * HS + j0 + 4] = make_float4(cc[4], cc[5], cc[6], cc[7]);
        *(uint4*)&outHi[(size_t)b * LDA + HOFF + j0] = *(uint4*)h_hi;
        *(uint4*)&outLo[(size_t)b * LDA + HOFF + j0] = *(uint4*)h_lo;
    } else if (step >= 1) {
        // key cols: relu -> Mk slot step-1
#pragma unroll
        for (int mi = 0; mi < 2; mi++)
#pragma unroll
            for (int ni = 0; ni < 4; ni++)
#pragma unroll
                for (int r_ = 0; r_ < 4; r_++) {
                    int b = row0 + wm * 32 + mi * 16 + crow + r_;
                    int nl = wn * 64 + ni * 16 + lm;
                    float v = fmaxf(acc[mi][ni][r_] + biasN[n0 + nl], 0.f);
                    Mk[((size_t)(step - 1) * BATCH + b) * KS + (n0 - 2048 + nl)] = v;
                }
    }
}

// ---------------------------------------------------------------------------
// Context norm over T, writes zero row t=32.
// ---------------------------------------------------------------------------
__global__ void norm_k(float* __restrict__ z_pad, const float* __restrict__ gamma,
                       const float* __restrict__ beta)
{
    int b = blockIdx.x, zc = threadIdx.x;
    float* zb = z_pad + (size_t)b * (MM * ZS);
    float s = 0.f, s2 = 0.f;
    for (int t = 0; t < TT; t++) { float v = zb[t * ZS + zc]; s += v; s2 += v * v; }
    float mu = s * (1.f / 32.f);
    float var = s2 * (1.f / 32.f) - mu * mu;
    float rstd = 1.f / sqrtf(var + 1e-8f);
    float ga = gamma[zc], be = beta[zc];
    for (int t = 0; t < TT; t++) {
        float v = zb[t * ZS + zc];
        zb[t * ZS + zc] = (v - mu) * rstd * ga + be;
    }
    zb[TT * ZS + zc] = 0.f;
}

// ---------------------------------------------------------------------------
// Precompute attention weights + confidence sums (z-only, loop-invariant).
// ---------------------------------------------------------------------------
__global__ __launch_bounds__(256)
void scores_k(const float* __restrict__ z_pad, const float* __restrict__ cg_p,
              const float* __restrict__ cb_p, float* __restrict__ watt,
              float* __restrict__ wc)
{
    __shared__ float zs[MM * 129];
    int b = blockIdx.x, tid = threadIdx.x;
    const float* zb = z_pad + (size_t)b * (MM * ZS);
    for (int i = tid; i < MM * ZS; i += 256) {
        int m = i >> 7, k = i & 127;
        zs[m * 129 + k] = zb[i];
    }
    __syncthreads();
    float cg = cg_p[0], cb = cb_p[0];
    int wid = tid >> 6, lane = tid & 63;
    for (int t = 1 + wid; t <= 32; t += 4) {
        int m = lane;
        float s = -3.0e38f;
        if (m < t) {
            const float* zt = &zs[t * 129];
            const float* zm = &zs[m * 129];
            float acc = 0.f;
#pragma unroll 8
            for (int k = 0; k < ZS; k++) acc += zt[k] * zm[k];
            s = acc;
        }
        float mx = s;
        for (int off = 1; off < 64; off <<= 1) mx = fmaxf(mx, __shfl_xor(mx, off));
        float e = (m < t) ? expf(s - mx) : 0.f;
        float sum = e;
        for (int off = 1; off < 64; off <<= 1) sum += __shfl_xor(sum, off);
        float w = e / sum;
        if (m < t) watt[(b * MM + t) * MM + m] = w;
        float p = (m < t) ? w * sigf(s * cg + cb) : 0.f;
        for (int off = 1; off < 64; off <<= 1) p += __shfl_xor(p, off);
        if (lane == 0) wc[b * MM + t] = p;
    }
}

// ---------------------------------------------------------------------------
// Post-step: g gate + attention read -> key_r(t+1) (bf16 hi/lo).
// ---------------------------------------------------------------------------
__global__ __launch_bounds__(256)
void post_k(ushort* __restrict__ inpHi, ushort* __restrict__ inpLo,
            const float* __restrict__ W_g, const float* __restrict__ b_g,
            const float* __restrict__ watt, const float* __restrict__ wc,
            const float* __restrict__ Mk, int t)
{
    __shared__ float red[256];
    __shared__ float wts[32];
    __shared__ float gsh;
    int b = blockIdx.x, tid = threadIdx.x;
    ushort* rHi = inpHi + (size_t)b * LDA;
    ushort* rLo = inpLo + (size_t)b * LDA;
    float h1 = bf2f(rHi[HOFF + tid]) + bf2f(rLo[HOFF + tid]);
    float h2 = bf2f(rHi[HOFF + 256 + tid]) + bf2f(rLo[HOFF + 256 + tid]);
    red[tid] = h1 * W_g[tid] + h2 * W_g[tid + 256];
    if (tid < t) wts[tid] = watt[(b * MM + t) * MM + tid];
    __syncthreads();
    for (int s = 128; s > 0; s >>= 1) {
        if (tid < s) red[tid] += red[tid + s];
        __syncthreads();
    }
    if (tid == 0) gsh = sigf(red[0] + b_g[0]);
    __syncthreads();
    float g = gsh;
    float acc = 0.f;
    for (int m = 0; m < t; m++)
        acc += wts[m] * Mk[((size_t)m * BATCH + b) * KS + tid];
    float v = g * acc;
    uint u = __float_as_uint(v);
    rHi[tid] = (ushort)(u >> 16);
    float lo = v - __uint_as_float(u & 0xFFFF0000u);
    rLo[tid] = (ushort)(__float_as_uint(lo) >> 16);
    if (tid == 0) {
        float vc = g * wc[b * MM + t];
        uint uc = __float_as_uint(vc);
        rHi[256] = (ushort)(uc >> 16);
        float lc = vc - __uint_as_float(uc & 0xFFFF0000u);
        rLo[256] = (ushort)(__float_as_uint(lc) >> 16);
    }
}

// ---------------------------------------------------------------------------
// Final y + argmax.
// ---------------------------------------------------------------------------
__global__ void y_k(const ushort* __restrict__ inpHi, const ushort* __restrict__ inpLo,
                    const float* __restrict__ W_y, const float* __restrict__ b_y,
                    float* __restrict__ out)
{
    int b = blockIdx.x, lane = threadIdx.x;
    const ushort* hHi = inpHi + (size_t)b * LDA + HOFF;
    const ushort* hLo = inpLo + (size_t)b * LDA + HOFF;
    float a0 = 0, a1 = 0, a2 = 0, a3 = 0;
    for (int r = 0; r < 8; r++) {
        int k = lane + r * 64;
        float hv = bf2f(hHi[k]) + bf2f(hLo[k]);
        a0 += hv * W_y[k];
        a1 += hv * W_y[512 + k];
        a2 += hv * W_y[1024 + k];
        a3 += hv * W_y[1536 + k];
    }
    for (int off = 32; off > 0; off >>= 1) {
        a0 += __shfl_xor(a0, off);
        a1 += __shfl_xor(a1, off);
        a2 += __shfl_xor(a2, off);
        a3 += __shfl_xor(a3, off);
    }
    if (lane == 0) {
        float y0 = a0 + b_y[0], y1 = a1 + b_y[1], y2 = a2 + b_y[2], y3 = a3 + b_y[3];
        out[b * 4 + 0] = y0; out[b * 4 + 1] = y1; out[b * 4 + 2] = y2; out[b * 4 + 3] = y3;
        int best = 0; float bv = y0;
        if (y1 > bv) { bv = y1; best = 1; }
        if (y2 > bv) { bv = y2; best = 2; }
        if (y3 > bv) { bv = y3; best = 3; }
        out[2048 + b] = (float)best;
    }
}

// ---------------------------------------------------------------------------
extern "C" void kernel_launch(void* const* d_in, const int* in_sizes, int n_in,
                              void* d_out, int out_size, void* d_ws, size_t ws_size,
                              hipStream_t stream)
{
    const float* x_seq = (const float*)d_in[0];
    const float* W_enc = (const float*)d_in[1];
    const float* gamma = (const float*)d_in[2];
    const float* beta  = (const float*)d_in[3];
    const float* W_ih  = (const float*)d_in[4];
    const float* W_hh  = (const float*)d_in[5];
    const float* b_ih  = (const float*)d_in[6];
    const float* b_hh  = (const float*)d_in[7];
    const float* W_key = (const float*)d_in[8];
    const float* b_key = (const float*)d_in[9];
    const float* W_g   = (const float*)d_in[10];
    const float* b_g   = (const float*)d_in[11];
    const float* cgain = (const float*)d_in[12];
    const float* cbias = (const float*)d_in[13];
    const float* W_y   = (const float*)d_in[14];
    const float* b_y   = (const float*)d_in[15];

    float* ws    = (float*)d_ws;
    float* z_pad = ws;                          // 2,162,688 f
    float* watt  = z_pad + 2162688;             // 557,568 f
    float* wcv   = watt + 557568;               // 16,896 f
    float* Mk    = wcv + 16896;                 // 4,194,304 f
    float* biasN = Mk + 4194304;                // 2,304 f
    float* cst   = biasN + 2304;                // 262,144 f
    ushort* inpHi0 = (ushort*)(cst + 262144);   // 409,600 us each
    ushort* inpLo0 = inpHi0 + 409600;
    ushort* inpHi1 = inpLo0 + 409600;
    ushort* inpLo1 = inpHi1 + 409600;
    ushort* Wpk  = inpLo1 + 409600;             // GP = 3,686,400 us
    ushort* Epk  = Wpk + GP;                    // EP = 262,144 us

    // zero c-state + all 4 input ping-pong buffers (contiguous region)
    hipMemsetAsync(cst, 0, 262144 * sizeof(float) + 4 * 409600 * sizeof(ushort), stream);

    prep_w<<<(GP + EP + 255) / 256, 256, 0, stream>>>(
        W_ih, W_hh, W_key, b_ih, b_hh, b_key, W_enc, Wpk, Epk, biasN);

    // encoder: [16384 x 1024] @ [1024 x 128] -> z_pad
    gemm_mfma<0, false><<<256, 256, 0, stream>>>(
        x_seq, nullptr, nullptr, 1024, Epk, ESLICE,
        z_pad, nullptr, nullptr, nullptr, nullptr, nullptr, 0);
    norm_k<<<512, 128, 0, stream>>>(z_pad, gamma, beta);
    scores_k<<<512, 256, 0, stream>>>(z_pad, cgain, cbias, watt, wcv);

    for (int t = 0; t <= 32; t++) {
        ushort* inHiC = (t & 1) ? inpHi1 : inpHi0;
        ushort* inLoC = (t & 1) ? inpLo1 : inpLo0;
        ushort* inHiN = (t & 1) ? inpHi0 : inpHi1;
        ushort* inLoN = (t & 1) ? inpLo0 : inpLo1;
        gemm_mfma<1, true><<<GTILES * 8, 256, 0, stream>>>(
            nullptr, inHiC, inLoC, LDA, Wpk, GSLICE,
            nullptr, inHiN, inLoN, biasN, cst, Mk, t);
        if (t >= 1 && t <= 31)
            post_k<<<512, 256, 0, stream>>>(inHiN, inLoN, W_g, b_g, watt, wcv, Mk, t);
    }
    y_k<<<512, 64, 0, stream>>>(inpHi1, inpLo1, W_y, b_y, (float*)d_out);
}

// Round 6
// 1221.277 us; speedup vs baseline: 1.4395x; 1.4395x over previous
//
#include <hip/hip_runtime.h>
#include <math.h>

typedef unsigned short ushort;
typedef unsigned int uint;
typedef __bf16 bf16x8 __attribute__((ext_vector_type(8)));
typedef float f32x4 __attribute__((ext_vector_type(4)));

// Problem constants
#define ZS    128
#define KS    256
#define HS    512
#define BATCH 512
#define TT    32
#define MM    33
#define HOFF  272      // k: 0..255 key_r, 256 conf, 257..271 pad, 272..783 h, 784..799 pad
// packed A: [mt(32)][s(25)][hi/lo(2)][lane(64)][e(8)]  (bf16 fragment order)
#define APK   819200
// gates B: [G(16)][T(9)][s(25)][hi/lo(2)][lane(64)][e(8)]
#define GP    (16*9*25*2*512)
// encoder B: [T(8)][s(32)][hi/lo(2)][lane(64)][e(8)]
#define EP    (8*32*2*512)

static __device__ __forceinline__ float sigf(float x) { return 1.f / (1.f + expf(-x)); }
static __device__ __forceinline__ float bf2f(ushort u) { return __uint_as_float((uint)u << 16); }
static __device__ __forceinline__ ushort f2hi(float v) { return (ushort)(__float_as_uint(v) >> 16); }
static __device__ __forceinline__ ushort f2lo(float v) {
    uint u = __float_as_uint(v);
    float lo = v - __uint_as_float(u & 0xFFFF0000u);
    return (ushort)(__float_as_uint(lo) >> 16);
}

// ---------------------------------------------------------------------------
// Weight prep into MFMA-fragment-packed streams.
// Gate col map: n-group G owns units 32G..32G+31 (tiles 0-7: quad=T>>2,
// gate=T&3, unit=32G+16*quad+(lane&15)) + key cols 16G..16G+15 (tile 8).
// ---------------------------------------------------------------------------
__global__ void prep_w(const float* __restrict__ W_ih, const float* __restrict__ W_hh,
                       const float* __restrict__ W_key, const float* __restrict__ b_ih,
                       const float* __restrict__ b_hh, const float* __restrict__ b_key,
                       const float* __restrict__ W_enc,
                       ushort* __restrict__ Wpk, ushort* __restrict__ Epk,
                       float* __restrict__ biasPk)
{
    int idx = blockIdx.x * 256 + threadIdx.x;
    if (idx < GP) {
        int e = idx & 7, r = idx >> 3;
        int l = r & 63; r >>= 6;
        int h = r & 1;  r >>= 1;
        int s = r % 25; r /= 25;
        int T = r % 9,  G = r / 9;
        int k = s * 32 + ((l >> 4) << 3) + e;
        int c16 = l & 15;
        float v = 0.f;
        if (T < 8) {
            int unit = G * 32 + (T >> 2) * 16 + c16;
            int wrow = (T & 3) * 512 + unit;
            if (k < 257) v = W_ih[wrow * 257 + k];
            else if (k >= HOFF && k < HOFF + 512) v = W_hh[wrow * 512 + (k - HOFF)];
        } else {
            int krow = G * 16 + c16;
            if (k >= HOFF && k < HOFF + 512) v = W_key[krow * 512 + (k - HOFF)];
        }
        Wpk[idx] = h ? f2lo(v) : f2hi(v);
    } else if (idx < GP + EP) {
        int q = idx - GP;
        int e = q & 7, r = q >> 3;
        int l = r & 63; r >>= 6;
        int h = r & 1;  r >>= 1;
        int s = r & 31; int T = r >> 5;
        int k = s * 32 + ((l >> 4) << 3) + e;
        int n = T * 16 + (l & 15);
        float v = W_enc[k * 128 + n];
        Epk[q] = h ? f2lo(v) : f2hi(v);
    } else if (idx < GP + EP + 2304) {
        int q = idx - GP - EP;
        int G = q / 144, rr = q - G * 144, T = rr >> 4, c16 = rr & 15;
        float bv;
        if (T < 8) {
            int unit = G * 32 + (T >> 2) * 16 + c16;
            int wrow = (T & 3) * 512 + unit;
            bv = b_ih[wrow] + b_hh[wrow];
        } else bv = b_key[G * 16 + c16];
        biasPk[q] = bv;
    }
}

// ---------------------------------------------------------------------------
// Gates GEMM: no LDS, no barriers. 256 blocks = 16 m-groups (32 rows) x
// 16 n-groups (8 gate tiles + 1 key tile). Wave (wm,wn): m-tile my*2+wm,
// tiles {wn*4..wn*4+3, 8}. 3-phase register prefetch from L2.
// Epilogue: lane's acc[0..3][r] = i,f,g,o of one unit -> fused LSTM cell,
// h written packed-bf16-hi/lo into next step's A. acc[4] -> relu -> Mk.
// ---------------------------------------------------------------------------
__global__ __launch_bounds__(256)
void gates_k(const ushort* __restrict__ inPk, const ushort* __restrict__ Wpk,
             const float* __restrict__ biasPk, float* __restrict__ cst,
             float* __restrict__ Mk, ushort* __restrict__ outPk, int step)
{
    const int flat = blockIdx.x;
    const int G  = (flat & 7) * 2 + ((flat >> 3) & 1);   // XCD-resident n-group
    const int my = flat >> 4;
    const int tid = threadIdx.x;
    const int l = tid & 63, w = tid >> 6, wm = w >> 1, wn = w & 1;
    const int mt = my * 2 + wm;
    const int c16 = l & 15;

    const ushort* Ab = inPk + (size_t)mt * 25600 + l * 8;
    const ushort* Bb[5];
#pragma unroll
    for (int ti = 0; ti < 5; ti++) {
        int T = (ti < 4) ? (wn * 4 + ti) : 8;
        Bb[ti] = Wpk + (size_t)(G * 9 + T) * 25600 + l * 8;
    }

    f32x4 acc[5];
#pragma unroll
    for (int i = 0; i < 5; i++) acc[i] = (f32x4){0.f, 0.f, 0.f, 0.f};

    bf16x8 a_[3][2], b_[3][5][2];
    auto LD = [&](int s, int ph) {
        a_[ph][0] = *(const bf16x8*)(Ab + (s * 2 + 0) * 512);
        a_[ph][1] = *(const bf16x8*)(Ab + (s * 2 + 1) * 512);
#pragma unroll
        for (int ti = 0; ti < 5; ti++) {
            b_[ph][ti][0] = *(const bf16x8*)(Bb[ti] + (s * 2 + 0) * 512);
            b_[ph][ti][1] = *(const bf16x8*)(Bb[ti] + (s * 2 + 1) * 512);
        }
    };

    LD(0, 0); LD(1, 1);
#pragma unroll
    for (int s = 0; s < 25; s++) {
        const int ph = s % 3;
        if (s + 2 < 25) LD(s + 2, (s + 2) % 3);
        const bf16x8 ah = a_[ph][0], al = a_[ph][1];
#pragma unroll
        for (int ti = 0; ti < 5; ti++) {
            acc[ti] = __builtin_amdgcn_mfma_f32_16x16x32_bf16(ah, b_[ph][ti][0], acc[ti], 0, 0, 0);
            acc[ti] = __builtin_amdgcn_mfma_f32_16x16x32_bf16(ah, b_[ph][ti][1], acc[ti], 0, 0, 0);
            acc[ti] = __builtin_amdgcn_mfma_f32_16x16x32_bf16(al, b_[ph][ti][0], acc[ti], 0, 0, 0);
        }
    }

    // ---- epilogue: LSTM cell, no cross-lane exchange needed
    const int crow = (l >> 4) << 2;
    const int row0 = my * 32 + wm * 16 + crow;
    const int u = G * 32 + wn * 16 + c16;
    const float bi  = biasPk[(G * 9 + wn * 4 + 0) * 16 + c16];
    const float bf_ = biasPk[(G * 9 + wn * 4 + 1) * 16 + c16];
    const float bg  = biasPk[(G * 9 + wn * 4 + 2) * 16 + c16];
    const float bo  = biasPk[(G * 9 + wn * 4 + 3) * 16 + c16];
    const int kk = HOFF + u, sh = kk >> 5, kin = kk & 31;
    const int lgrp = (kin >> 3) << 4, e = kin & 7;
#pragma unroll
    for (int rr = 0; rr < 4; rr++) {
        int row = row0 + rr;
        float co = cst[row * HS + u];
        float ig = sigf(acc[0][rr] + bi), fg = sigf(acc[1][rr] + bf_);
        float gg = tanhf(acc[2][rr] + bg), og = sigf(acc[3][rr] + bo);
        float cn = fg * co + ig * gg;
        float hv = og * tanhf(cn);
        cst[row * HS + u] = cn;
        size_t o0 = ((size_t)((row >> 4) * 25 + sh) * 2) * 512 + (lgrp | (row & 15)) * 8 + e;
        outPk[o0]       = f2hi(hv);
        outPk[o0 + 512] = f2lo(hv);
    }
    if (wn == 1 && step >= 1) {
        float bk = biasPk[(G * 9 + 8) * 16 + c16];
        int kc = G * 16 + c16;
#pragma unroll
        for (int rr = 0; rr < 4; rr++) {
            int row = row0 + rr;
            float v = fmaxf(acc[4][rr] + bk, 0.f);
            Mk[((size_t)(step - 1) * BATCH + row) * KS + kc] = v;
        }
    }
}

// ---------------------------------------------------------------------------
// Encoder GEMM: same registered-stream structure; A fp32 from HBM, split
// hi/lo in-lane (fragment layout is lane-local: 8 consecutive k per lane).
// 256 blocks x 64 rows; B (512 KB packed) L2-resident.
// ---------------------------------------------------------------------------
__global__ __launch_bounds__(256)
void enc_k(const float* __restrict__ x, const ushort* __restrict__ Epk,
           float* __restrict__ z_pad)
{
    const int flat = blockIdx.x, tid = threadIdx.x;
    const int l = tid & 63, w = tid >> 6, wm = w >> 1, wn = w & 1;
    const int c16 = l & 15, kq = l >> 4;

    const float* Arow[2];
#pragma unroll
    for (int mi = 0; mi < 2; mi++) {
        int mtile = flat * 4 + wm * 2 + mi;
        Arow[mi] = x + (size_t)(mtile * 16 + c16) * 1024 + kq * 8;
    }
    const ushort* Bb[4];
#pragma unroll
    for (int ti = 0; ti < 4; ti++)
        Bb[ti] = Epk + (size_t)(wn * 4 + ti) * 32768 + l * 8;

    f32x4 acc[2][4];
#pragma unroll
    for (int mi = 0; mi < 2; mi++)
#pragma unroll
        for (int ti = 0; ti < 4; ti++) acc[mi][ti] = (f32x4){0.f, 0.f, 0.f, 0.f};

    float4 af[3][2][2];
    bf16x8 bb[3][4][2];
    auto LD = [&](int s, int ph) {
#pragma unroll
        for (int mi = 0; mi < 2; mi++) {
            af[ph][mi][0] = *(const float4*)(Arow[mi] + s * 32);
            af[ph][mi][1] = *(const float4*)(Arow[mi] + s * 32 + 4);
        }
#pragma unroll
        for (int ti = 0; ti < 4; ti++) {
            bb[ph][ti][0] = *(const bf16x8*)(Bb[ti] + (s * 2 + 0) * 512);
            bb[ph][ti][1] = *(const bf16x8*)(Bb[ti] + (s * 2 + 1) * 512);
        }
    };

    LD(0, 0); LD(1, 1);
#pragma unroll
    for (int s = 0; s < 32; s++) {
        const int ph = s % 3;
        if (s + 2 < 32) LD(s + 2, (s + 2) % 3);
#pragma unroll
        for (int mi = 0; mi < 2; mi++) {
            float fv[8];
            *(float4*)&fv[0] = af[ph][mi][0];
            *(float4*)&fv[4] = af[ph][mi][1];
            ushort hi8[8] __attribute__((aligned(16)));
            ushort lo8[8] __attribute__((aligned(16)));
#pragma unroll
            for (int e2 = 0; e2 < 8; e2++) { hi8[e2] = f2hi(fv[e2]); lo8[e2] = f2lo(fv[e2]); }
            bf16x8 ah = *(bf16x8*)hi8, al = *(bf16x8*)lo8;
#pragma unroll
            for (int ti = 0; ti < 4; ti++) {
                acc[mi][ti] = __builtin_amdgcn_mfma_f32_16x16x32_bf16(ah, bb[ph][ti][0], acc[mi][ti], 0, 0, 0);
                acc[mi][ti] = __builtin_amdgcn_mfma_f32_16x16x32_bf16(ah, bb[ph][ti][1], acc[mi][ti], 0, 0, 0);
                acc[mi][ti] = __builtin_amdgcn_mfma_f32_16x16x32_bf16(al, bb[ph][ti][0], acc[mi][ti], 0, 0, 0);
            }
        }
    }
    const int crow = (l >> 4) << 2;
#pragma unroll
    for (int mi = 0; mi < 2; mi++) {
        int mtile = flat * 4 + wm * 2 + mi;
#pragma unroll
        for (int ti = 0; ti < 4; ti++) {
            int z = (wn * 4 + ti) * 16 + c16;
#pragma unroll
            for (int rr = 0; rr < 4; rr++) {
                int m = mtile * 16 + crow + rr;
                z_pad[(size_t)(m >> 5) * (MM * ZS) + (m & 31) * ZS + z] = acc[mi][ti][rr];
            }
        }
    }
}

// ---------------------------------------------------------------------------
// Context norm over T, writes zero row t=32.
// ---------------------------------------------------------------------------
__global__ void norm_k(float* __restrict__ z_pad, const float* __restrict__ gamma,
                       const float* __restrict__ beta)
{
    int b = blockIdx.x, zc = threadIdx.x;
    float* zb = z_pad + (size_t)b * (MM * ZS);
    float s = 0.f, s2 = 0.f;
    for (int t = 0; t < TT; t++) { float v = zb[t * ZS + zc]; s += v; s2 += v * v; }
    float mu = s * (1.f / 32.f);
    float var = s2 * (1.f / 32.f) - mu * mu;
    float rstd = 1.f / sqrtf(var + 1e-8f);
    float ga = gamma[zc], be = beta[zc];
    for (int t = 0; t < TT; t++) {
        float v = zb[t * ZS + zc];
        zb[t * ZS + zc] = (v - mu) * rstd * ga + be;
    }
    zb[TT * ZS + zc] = 0.f;
}

// ---------------------------------------------------------------------------
// Precompute attention weights + confidence sums (z-only, loop-invariant).
// ---------------------------------------------------------------------------
__global__ __launch_bounds__(256)
void scores_k(const float* __restrict__ z_pad, const float* __restrict__ cg_p,
              const float* __restrict__ cb_p, float* __restrict__ watt,
              float* __restrict__ wc)
{
    __shared__ float zs[MM * 129];
    int b = blockIdx.x, tid = threadIdx.x;
    const float* zb = z_pad + (size_t)b * (MM * ZS);
    for (int i = tid; i < MM * ZS; i += 256) {
        int m = i >> 7, k = i & 127;
        zs[m * 129 + k] = zb[i];
    }
    __syncthreads();
    float cg = cg_p[0], cb = cb_p[0];
    int wid = tid >> 6, lane = tid & 63;
    for (int t = 1 + wid; t <= 32; t += 4) {
        int m = lane;
        float s = -3.0e38f;
        if (m < t) {
            const float* zt = &zs[t * 129];
            const float* zm = &zs[m * 129];
            float acc = 0.f;
#pragma unroll 8
            for (int k = 0; k < ZS; k++) acc += zt[k] * zm[k];
            s = acc;
        }
        float mx = s;
        for (int off = 1; off < 64; off <<= 1) mx = fmaxf(mx, __shfl_xor(mx, off));
        float e = (m < t) ? expf(s - mx) : 0.f;
        float sum = e;
        for (int off = 1; off < 64; off <<= 1) sum += __shfl_xor(sum, off);
        float w2 = e / sum;
        if (m < t) watt[(b * MM + t) * MM + m] = w2;
        float p = (m < t) ? w2 * sigf(s * cg + cb) : 0.f;
        for (int off = 1; off < 64; off <<= 1) p += __shfl_xor(p, off);
        if (lane == 0) wc[b * MM + t] = p;
    }
}

// ---------------------------------------------------------------------------
// Post-step: g gate + attention read -> key_r(t+1) packed into the buffer
// gates(t+1) reads (same buffer gates(t) wrote h into; disjoint k-range).
// ---------------------------------------------------------------------------
__global__ __launch_bounds__(256)
void post_k(ushort* __restrict__ pk, const float* __restrict__ W_g,
            const float* __restrict__ b_g, const float* __restrict__ watt,
            const float* __restrict__ wcv, const float* __restrict__ Mk, int t)
{
    __shared__ float red[256];
    __shared__ float wts[32];
    __shared__ float gsh;
    int b = blockIdx.x, tid = threadIdx.x;
    int mt = b >> 4, bl15 = b & 15;
    float hsum = 0.f;
#pragma unroll
    for (int q = 0; q < 2; q++) {
        int j = tid + q * 256;
        int kk = HOFF + j, sh = kk >> 5, kin = kk & 31;
        size_t o = ((size_t)(mt * 25 + sh) * 2) * 512 + ((((kin >> 3) << 4)) | bl15) * 8 + (kin & 7);
        float hv = bf2f(pk[o]) + bf2f(pk[o + 512]);
        hsum += hv * W_g[j];
    }
    red[tid] = hsum;
    if (tid < t) wts[tid] = watt[(b * MM + t) * MM + tid];
    __syncthreads();
    for (int s2 = 128; s2 > 0; s2 >>= 1) {
        if (tid < s2) red[tid] += red[tid + s2];
        __syncthreads();
    }
    if (tid == 0) gsh = sigf(red[0] + b_g[0]);
    __syncthreads();
    float g = gsh;
    float acc = 0.f;
    for (int m = 0; m < t; m++)
        acc += wts[m] * Mk[((size_t)m * BATCH + b) * KS + tid];
    float v = g * acc;
    {
        int sh = tid >> 5, kin = tid & 31;
        size_t o = ((size_t)(mt * 25 + sh) * 2) * 512 + (((kin >> 3) << 4) | bl15) * 8 + (kin & 7);
        pk[o]       = f2hi(v);
        pk[o + 512] = f2lo(v);
    }
    if (tid == 0) {
        float vc = g * wcv[b * MM + t];
        size_t o = ((size_t)(mt * 25 + 8) * 2) * 512 + bl15 * 8;   // k=256
        pk[o]       = f2hi(vc);
        pk[o + 512] = f2lo(vc);
    }
}

// ---------------------------------------------------------------------------
// Final y + argmax (reads packed h).
// ---------------------------------------------------------------------------
__global__ void y_k(const ushort* __restrict__ pk, const float* __restrict__ W_y,
                    const float* __restrict__ b_y, float* __restrict__ out)
{
    int b = blockIdx.x, lane = threadIdx.x;
    int mt = b >> 4, bl15 = b & 15;
    float a0 = 0, a1 = 0, a2 = 0, a3 = 0;
    for (int r = 0; r < 8; r++) {
        int j = lane + r * 64;
        int kk = HOFF + j, sh = kk >> 5, kin = kk & 31;
        size_t o = ((size_t)(mt * 25 + sh) * 2) * 512 + (((kin >> 3) << 4) | bl15) * 8 + (kin & 7);
        float hv = bf2f(pk[o]) + bf2f(pk[o + 512]);
        a0 += hv * W_y[j];
        a1 += hv * W_y[512 + j];
        a2 += hv * W_y[1024 + j];
        a3 += hv * W_y[1536 + j];
    }
    for (int off = 32; off > 0; off >>= 1) {
        a0 += __shfl_xor(a0, off);
        a1 += __shfl_xor(a1, off);
        a2 += __shfl_xor(a2, off);
        a3 += __shfl_xor(a3, off);
    }
    if (lane == 0) {
        float y0 = a0 + b_y[0], y1 = a1 + b_y[1], y2 = a2 + b_y[2], y3 = a3 + b_y[3];
        out[b * 4 + 0] = y0; out[b * 4 + 1] = y1; out[b * 4 + 2] = y2; out[b * 4 + 3] = y3;
        int best = 0; float bv = y0;
        if (y1 > bv) { bv = y1; best = 1; }
        if (y2 > bv) { bv = y2; best = 2; }
        if (y3 > bv) { bv = y3; best = 3; }
        out[2048 + b] = (float)best;
    }
}

// ---------------------------------------------------------------------------
extern "C" void kernel_launch(void* const* d_in, const int* in_sizes, int n_in,
                              void* d_out, int out_size, void* d_ws, size_t ws_size,
                              hipStream_t stream)
{
    const float* x_seq = (const float*)d_in[0];
    const float* W_enc = (const float*)d_in[1];
    const float* gamma = (const float*)d_in[2];
    const float* beta  = (const float*)d_in[3];
    const float* W_ih  = (const float*)d_in[4];
    const float* W_hh  = (const float*)d_in[5];
    const float* b_ih  = (const float*)d_in[6];
    const float* b_hh  = (const float*)d_in[7];
    const float* W_key = (const float*)d_in[8];
    const float* b_key = (const float*)d_in[9];
    const float* W_g   = (const float*)d_in[10];
    const float* b_g   = (const float*)d_in[11];
    const float* cgain = (const float*)d_in[12];
    const float* cbias = (const float*)d_in[13];
    const float* W_y   = (const float*)d_in[14];
    const float* b_y   = (const float*)d_in[15];

    float* ws     = (float*)d_ws;
    float* z_pad  = ws;                          // 2,162,688 f
    float* watt   = z_pad + 2162688;             // 557,568 f
    float* wcv    = watt + 557568;               // 16,896 f
    float* Mk     = wcv + 16896;                 // 4,194,304 f
    float* biasPk = Mk + 4194304;                // 2,304 f
    float* cst    = biasPk + 2304;               // 262,144 f
    ushort* inPk0 = (ushort*)(cst + 262144);     // 819,200 us
    ushort* inPk1 = inPk0 + APK;                 // 819,200 us
    ushort* Wpk   = inPk1 + APK;                 // 3,686,400 us
    ushort* Epk   = Wpk + GP;                    // 262,144 us

    // zero c-state + both packed input buffers (contiguous): covers t=0
    // zero-A, zero key_r(1), and all pad columns for every step.
    hipMemsetAsync(cst, 0, 262144 * sizeof(float) + 2 * APK * sizeof(ushort), stream);

    prep_w<<<(GP + EP + 2304 + 255) / 256, 256, 0, stream>>>(
        W_ih, W_hh, W_key, b_ih, b_hh, b_key, W_enc, Wpk, Epk, biasPk);

    enc_k<<<256, 256, 0, stream>>>(x_seq, Epk, z_pad);
    norm_k<<<512, 128, 0, stream>>>(z_pad, gamma, beta);
    scores_k<<<512, 256, 0, stream>>>(z_pad, cgain, cbias, watt, wcv);

    for (int t = 0; t <= 32; t++) {
        ushort* inC = (t & 1) ? inPk1 : inPk0;
        ushort* inN = (t & 1) ? inPk0 : inPk1;
        gates_k<<<256, 256, 0, stream>>>(inC, Wpk, biasPk, cst, Mk, inN, t);
        if (t >= 1 && t <= 31)
            post_k<<<512, 256, 0, stream>>>(inN, W_g, b_g, watt, wcv, Mk, t);
    }
    y_k<<<512, 64, 0, stream>>>(inPk1, W_y, b_y, (float*)d_out);
}